// Round 2
// baseline (121.059 us; speedup 1.0000x reference)
//
#include <hip/hip_runtime.h>
#include <math.h>

#define BLK 256

// ---------------------------------------------------------------------------
// Rotated-box intersection area via Green's theorem (no polygon clipping):
// area(P∩Q) = 1/2 ∮ (x dy − y dx) = Σ P-edge pieces clipped to Q's AAB frame
// + Σ Q-edge pieces clipped to P's AAB frame + 1/2·cross(t, R·ΣΔ) translation
// correction (x dy − y dx is rotation-invariant).  Each piece is a branchless
// Liang-Barsky slab clip; empty clips give exactly-zero-length pieces.
//
// Memory structure (this revision): direct MLP'd loads (round-0 structure —
// the LDS-staged variant measured ~5 µs slower: the __syncthreads vmcnt-drain
// broke load/compute overlap). New: all stream-once arrays (box_preds,
// reg_targets, iou_preds, one_hot, weights, out) use non-temporal
// loads/stores so the 82 MB single-touch stream doesn't allocate/evict in
// L2/L3; anchors stay cached (re-read by the paired y-slice, which maps to
// the same XCD because gridDim.x = 1024 ≡ 0 mod 8). __launch_bounds__(256,4)
// caps VGPR at 128 to stay on the 16-waves/CU side of the occupancy cliff.
// ---------------------------------------------------------------------------

#define NTL(p)      __builtin_nontemporal_load(p)
#define NTS(v, p)   __builtin_nontemporal_store((v), (p))

__device__ __forceinline__ float clamp_mag(float x) {
    return copysignf(fmaxf(fabsf(x), 1e-30f), x);
}

// clip segment p + s*e, s in [0,1], to box [-hx,hx] x [-hy,hy]; r = 1/e (pre-clamped)
__device__ __forceinline__ void edge_piece(float px, float py, float ex, float ey,
                                           float rx, float ry, float hx, float hy,
                                           float& area2, float& Dx, float& Dy)
{
    float sx0 = (-hx - px) * rx, sx1 = (hx - px) * rx;
    float sy0 = (-hy - py) * ry, sy1 = (hy - py) * ry;
    float smin = fmaxf(fmaxf(fminf(sx0, sx1), fminf(sy0, sy1)), 0.0f);
    float smax = fminf(fminf(fmaxf(sx0, sx1), fmaxf(sy0, sy1)), 1.0f);
    smax = fmaxf(smax, smin);                  // empty -> zero-length at smin
    float ax = fmaf(smin, ex, px), ay = fmaf(smin, ey, py);
    float bx = fmaf(smax, ex, px), by = fmaf(smax, ey, py);
    float ux = bx - ax, uy = by - ay;          // exactly 0 when smin==smax
    area2 += fmaf(ax, uy, -(ay * ux));         // cross(a, b-a) == cross(a,b)
    Dx += ux; Dy += uy;
}

// Full pair IoU -> loss for one (pred, target) box pair sharing an anchor.
__device__ __forceinline__ float pair_loss(const float bp[5], const float rt[5],
                                           float xa, float ya, float dxa, float dya,
                                           float ra, float diag,
                                           float ip, int oh, float w)
{
    // decode P (pred) / Q (target): fields {x, y, dx, dy, r}
    float x1  = fmaf(bp[0], diag, xa);
    float y1  = fmaf(bp[1], diag, ya);
    float dx1 = __expf(bp[2]) * dxa;
    float dy1 = __expf(bp[3]) * dya;
    float r1  = bp[4] + ra;

    float x2  = fmaf(rt[0], diag, xa);
    float y2  = fmaf(rt[1], diag, ya);
    float dx2 = __expf(rt[2]) * dxa;
    float dy2 = __expf(rt[3]) * dya;
    float r2  = rt[4] + ra;

    float a1 = dx1 * dy1, a2 = dx2 * dy2;
    float h1x = 0.5f * dx1, h1y = 0.5f * dy1;
    float h2x = 0.5f * dx2, h2y = 0.5f * dy2;

    // P in Q's frame: p_Q = R(dr)·p_P + t
    float c2v = __cosf(r2), s2v = __sinf(r2);
    float dr  = r1 - r2;
    float cd  = __cosf(dr), sd = __sinf(dr);
    float ddx = x1 - x2, ddy = y1 - y2;
    float tx  = fmaf(c2v, ddx,  s2v * ddy);
    float ty  = fmaf(-s2v, ddx, c2v * ddy);

    // P half-edge vectors in Q frame
    float ux_ = h1x * cd,  uy_ = h1x * sd;
    float vx_ = -h1y * sd, vy_ = h1y * cd;
    // full edge vectors ±2u, ±2v and their shared reciprocals
    float eux = 2.0f * ux_, euy = 2.0f * uy_;
    float evx = 2.0f * vx_, evy = 2.0f * vy_;
    float ruxP = __fdividef(1.0f, clamp_mag(eux));
    float ruyP = __fdividef(1.0f, clamp_mag(euy));
    float rvxP = __fdividef(1.0f, clamp_mag(evx));
    float rvyP = __fdividef(1.0f, clamp_mag(evy));
    // corners (CCW)
    float p0x = tx + ux_ + vx_, p0y = ty + uy_ + vy_;
    float p1x = tx - ux_ + vx_, p1y = ty - uy_ + vy_;
    float p2x = tx - ux_ - vx_, p2y = ty - uy_ - vy_;
    float p3x = tx + ux_ - vx_, p3y = ty + uy_ - vy_;

    float area2 = 0.0f, dDx = 0.0f, dDy = 0.0f;
    edge_piece(p0x, p0y, -eux, -euy, -ruxP, -ruyP, h2x, h2y, area2, dDx, dDy);
    edge_piece(p1x, p1y, -evx, -evy, -rvxP, -rvyP, h2x, h2y, area2, dDx, dDy);
    edge_piece(p2x, p2y,  eux,  euy,  ruxP,  ruyP, h2x, h2y, area2, dDx, dDy);
    edge_piece(p3x, p3y,  evx,  evy,  rvxP,  rvyP, h2x, h2y, area2, dDx, dDy);

    // Q in P's frame: u' = R^T·(h2x,0), v' = R^T·(0,h2y), o = -R^T·t
    float upx = h2x * cd,  upy = -h2x * sd;
    float vpx = h2y * sd,  vpy = h2y * cd;
    float ox  = -(fmaf(cd, tx,  sd * ty));
    float oy  = -(fmaf(-sd, tx, cd * ty));
    float equx = 2.0f * upx, equy = 2.0f * upy;
    float eqvx = 2.0f * vpx, eqvy = 2.0f * vpy;
    float ruxQ = __fdividef(1.0f, clamp_mag(equx));
    float ruyQ = __fdividef(1.0f, clamp_mag(equy));
    float rvxQ = __fdividef(1.0f, clamp_mag(eqvx));
    float rvyQ = __fdividef(1.0f, clamp_mag(eqvy));
    float q0x = ox + upx + vpx, q0y = oy + upy + vpy;
    float q1x = ox - upx + vpx, q1y = oy - upy + vpy;
    float q2x = ox - upx - vpx, q2y = oy - upy - vpy;
    float q3x = ox + upx - vpx, q3y = oy + upy - vpy;

    float Dx = 0.0f, Dy = 0.0f;
    edge_piece(q0x, q0y, -equx, -equy, -ruxQ, -ruyQ, h1x, h1y, area2, Dx, Dy);
    edge_piece(q1x, q1y, -eqvx, -eqvy, -rvxQ, -rvyQ, h1x, h1y, area2, Dx, Dy);
    edge_piece(q2x, q2y,  equx,  equy,  ruxQ,  ruyQ, h1x, h1y, area2, Dx, Dy);
    edge_piece(q3x, q3y,  eqvx,  eqvy,  rvxQ,  rvyQ, h1x, h1y, area2, Dx, Dy);

    // translation correction: cross(t, R·D)
    float RDx = fmaf(cd, Dx, -(sd * Dy));
    float RDy = fmaf(sd, Dx,   cd * Dy);
    area2 += fmaf(tx, RDy, -(ty * RDx));

    float inter = 0.5f * fabsf(area2);
    float uni = fmaxf(a1 + a2 - inter, 1e-6f);
    float iou = __fdividef(inter, uni);

    float target = (oh > 0) ? iou : 0.0f;
    float z  = __fdividef(1.0f, 1.0f + __expf(-ip));   // sigmoid
    float pt = __logf(1.0f + __expf(z)) - z * target;  // logaddexp(0,z) - z*target
    return pt * w;
}

__global__ __launch_bounds__(BLK, 4)
void iou_pred_loss_kernel(const float* __restrict__ iou_preds,
                          const int*   __restrict__ one_hot,
                          const float* __restrict__ weights,
                          const float* __restrict__ anchors,
                          const float* __restrict__ box_preds,
                          const float* __restrict__ reg_targets,
                          float* __restrict__ out,
                          int N, int B)
{
    int tid   = threadIdx.x;
    int n_idx = blockIdx.x * BLK + tid;
    if (n_idx >= N) return;

    int yspan = gridDim.y;                 // = ceil(B/2)
    int b0 = blockIdx.y;
    int b1 = blockIdx.y + yspan;
    bool has2 = (b1 < B);
    size_t g0 = (size_t)b0 * N + n_idx;
    size_t g1 = (size_t)(has2 ? b1 : b0) * N + n_idx;

    // ---- issue ALL global loads up front (MLP) ----
    // anchors: cached loads (re-read by the paired y-slice on the same XCD)
    const float* an = anchors + (size_t)n_idx * 7;
    float xa = an[0], ya = an[1], dxa = an[3], dya = an[4], ra = an[6];

    // stream-once arrays: non-temporal (no L2/L3 allocation for 82 MB of
    // single-touch data)
    const float* bpp0 = box_preds   + g0 * 7;
    const float* rtp0 = reg_targets + g0 * 7;
    const float* bpp1 = box_preds   + g1 * 7;
    const float* rtp1 = reg_targets + g1 * 7;
    float bp0[5] = {NTL(bpp0+0), NTL(bpp0+1), NTL(bpp0+3), NTL(bpp0+4), NTL(bpp0+6)};
    float rt0[5] = {NTL(rtp0+0), NTL(rtp0+1), NTL(rtp0+3), NTL(rtp0+4), NTL(rtp0+6)};
    float bp1[5] = {NTL(bpp1+0), NTL(bpp1+1), NTL(bpp1+3), NTL(bpp1+4), NTL(bpp1+6)};
    float rt1[5] = {NTL(rtp1+0), NTL(rtp1+1), NTL(rtp1+3), NTL(rtp1+4), NTL(rtp1+6)};
    float ip0 = NTL(iou_preds + g0), ip1 = NTL(iou_preds + g1);
    int   oh0 = NTL(one_hot + g0),   oh1 = NTL(one_hot + g1);
    float w0  = NTL(weights + g0),   w1  = NTL(weights + g1);

    float diag = sqrtf(fmaf(dxa, dxa, dya * dya));

    float r0 = pair_loss(bp0, rt0, xa, ya, dxa, dya, ra, diag, ip0, oh0, w0);
    NTS(r0, out + g0);
    if (has2) {
        float r1 = pair_loss(bp1, rt1, xa, ya, dxa, dya, ra, diag, ip1, oh1, w1);
        NTS(r1, out + g1);
    }
}

extern "C" void kernel_launch(void* const* d_in, const int* in_sizes, int n_in,
                              void* d_out, int out_size, void* d_ws, size_t ws_size,
                              hipStream_t stream) {
    const float* iou_preds   = (const float*)d_in[0];
    const int*   one_hot     = (const int*)  d_in[1];
    const float* weights     = (const float*)d_in[2];
    const float* anchors     = (const float*)d_in[3];
    const float* box_preds   = (const float*)d_in[4];
    const float* reg_targets = (const float*)d_in[5];
    float* out = (float*)d_out;

    int total = in_sizes[0];       // B*N
    int N     = in_sizes[3] / 7;   // anchor count
    int B     = total / N;

    dim3 grid((N + BLK - 1) / BLK, (B + 1) / 2);
    iou_pred_loss_kernel<<<grid, dim3(BLK), 0, stream>>>(
        iou_preds, one_hot, weights, anchors, box_preds, reg_targets,
        out, N, B);
}